// Round 3
// baseline (3128.322 us; speedup 1.0000x reference)
//
#include <hip/hip_runtime.h>

typedef __bf16 bf16_t;
typedef __bf16 bf16x8 __attribute__((ext_vector_type(8)));
typedef float floatx4 __attribute__((ext_vector_type(4)));

#define GRU_STEPS 120
#define OUTC 31

// ws layout (bytes):
//   blob0 : [0, 524288)          bf16 [8][1024][32]  step-0 weights (x=0)
//   blob1 : [524288, 1048576)    bf16 [8][1024][32]  steady-state weights
//   woutp : [1048576, 1064960)   bf16 [32][256]      W_out padded to 32 rows
//   biasc : [1064960, 1069056)   f32  [1024]         combined gate biases
//   boutp : [1069056, 1069184)   f32  [32]           b_out padded

__global__ void repack_kernel(const float* __restrict__ Wih, const float* __restrict__ Whh,
                              const float* __restrict__ bih, const float* __restrict__ bhh,
                              const float* __restrict__ Wout, const float* __restrict__ bout,
                              bf16_t* __restrict__ blob0, bf16_t* __restrict__ blob1,
                              bf16_t* __restrict__ woutp, float* __restrict__ biasc,
                              float* __restrict__ boutp)
{
    int idx = blockIdx.x * blockDim.x + threadIdx.x;   // 0 .. 1024*256-1
    if (idx >= 1024 * 256) return;
    int n  = idx >> 8;    // blob column (gate output index), 0..1023
    int kk = idx & 255;   // k index, 0..255

    // blob column map: [0,512) r|z combined, [512,768) i_n (W_ih rows 512..767),
    //                  [768,1024) h_n (W_hh rows 512..767)
    float vih = (n < 768) ? Wih[n * 256 + kk] : 0.f;
    float vhh = (n < 512) ? Whh[n * 256 + kk]
                          : ((n >= 768) ? Whh[(n - 256) * 256 + kk] : 0.f);
    float b1 = (n < 512) ? (vih + vhh) : ((n < 768) ? vih : vhh); // t>=1 (x==h)
    float b0 = (n < 512) ? vhh : ((n < 768) ? 0.f : vhh);         // t==0 (x==0)

    int c = kk >> 5, kloc = kk & 31;
    int off = c * (1024 * 32) + n * 32 + kloc;   // [chunk][n][k] k-contiguous
    blob0[off] = (bf16_t)b0;
    blob1[off] = (bf16_t)b1;

    if (n < 32) woutp[n * 256 + kk] = (bf16_t)((n < OUTC) ? Wout[n * 256 + kk] : 0.f);
    if (idx < 1024) {
        float bb = (idx < 512) ? (bih[idx] + bhh[idx])
                               : ((idx < 768) ? bih[idx] : bhh[idx - 256]);
        biasc[idx] = bb;
    }
    if (idx < 32) boutp[idx] = (idx < OUTC) ? bout[idx] : 0.f;
}

__device__ __forceinline__ float sigmoid_f(float x) {
    return __builtin_amdgcn_rcpf(1.f + __expf(-x));
}
__device__ __forceinline__ float tanh_f(float x) {
    // 1 - 2/(1+e^{2x}): exact at +/-inf, monotone, ~1ulp rcp/exp
    return 1.f - 2.f * __builtin_amdgcn_rcpf(1.f + __expf(2.f * x));
}

// async global -> LDS, 16B per lane. Deposits lane i's 16B at lds_base + i*16.
__device__ __forceinline__ void gload16(const void* g, void* l) {
    __builtin_amdgcn_global_load_lds(
        (const __attribute__((address_space(1))) unsigned int*)g,
        (__attribute__((address_space(3))) unsigned int*)l, 16, 0, 0);
}

// steady-state counted wait: retire the oldest staged group (4 loads), keep
// the 8 younger loads (2 groups) in flight. Stores at step boundaries only
// make this stricter (over-wait), never under-wait.
#define VMWAIT8 asm volatile("s_waitcnt vmcnt(8)" ::: "memory")

// One GRU step. ROT = staging-buffer rotation for this step (16 groups/step,
// 16 mod 3 == 1, so rotation advances by 1 per step; handled by 3 template
// instantiations so every LDS address is a compile-time constant).
//
// B-slot s (0..63) = c*8 + g*2 + nt. Group p = s>>2 (4 slots, 4 KB/wave).
// Group p lives in staging buffer (ROT+p)%3. Issue schedule: after consuming
// group p, issue group p+3 into the buffer p occupied (p+3 ≡ p mod 3).
// Groups 16..18 belong to the NEXT step (always blob1). 12 loads in flight.
template<int ROT>
__device__ __forceinline__ void gru_step(
    int t, const char* __restrict__ cur, const char* __restrict__ b1p,
    bf16_t* __restrict__ Abuf, bf16_t* __restrict__ WoutB,
    char* __restrict__ SB,
    float (&h)[2][4][4], const float (&biasv)[4][2], float ybias,
    float* __restrict__ out, int rowBase, int w, int l16, int q,
    int laneByte, int ldsLane)
{
    floatx4 acc[4][2][4];
#pragma unroll
    for (int g = 0; g < 4; ++g)
#pragma unroll
        for (int nt = 0; nt < 2; ++nt) {
            float b = biasv[g][nt];
            floatx4 binit = {b, b, b, b};
#pragma unroll
            for (int mt = 0; mt < 4; ++mt) acc[g][nt][mt] = binit;
        }

#pragma unroll
    for (int c = 0; c < 8; ++c) {      // K chunks of 32; 2 groups per chunk
        bf16x8 afr[4];
#pragma unroll
        for (int mt = 0; mt < 4; ++mt)
            afr[mt] = *reinterpret_cast<const bf16x8*>(
                &Abuf[(mt * 16 + l16) * 264 + c * 32 + q * 8]);

        VMWAIT8;   // group 2c staged
#pragma unroll
        for (int g = 0; g < 2; ++g)
#pragma unroll
            for (int nt = 0; nt < 2; ++nt) {
                const int buf = (ROT + 2 * c) % 3;
                const int j   = g * 2 + nt;
                const bf16x8 bfr = *reinterpret_cast<const bf16x8*>(
                    SB + buf * 32768 + j * 1024 + ldsLane);
#pragma unroll
                for (int mt = 0; mt < 4; ++mt)
                    acc[g][nt][mt] = __builtin_amdgcn_mfma_f32_16x16x32_bf16(
                        afr[mt], bfr, acc[g][nt][mt], 0, 0, 0);
            }
        {   // issue group 2c+3
            const int P = 2 * c + 3;
            const char* BB = (P < 16) ? cur : b1p;
            const int PL  = P & 15;
            const int buf = (ROT + P) % 3;
#pragma unroll
            for (int j = 0; j < 4; ++j) {
                const int s = PL * 4 + j;
                const int sc = s >> 3, sg = (s >> 1) & 3, sn = s & 1;
                gload16(BB + sc * 65536 + sg * 16384 + sn * 1024 + laneByte,
                        SB + buf * 32768 + w * 4096 + j * 1024);
            }
        }
        VMWAIT8;   // group 2c+1 staged
#pragma unroll
        for (int g = 2; g < 4; ++g)
#pragma unroll
            for (int nt = 0; nt < 2; ++nt) {
                const int buf = (ROT + 2 * c + 1) % 3;
                const int j   = (g & 1) * 2 + nt;
                const bf16x8 bfr = *reinterpret_cast<const bf16x8*>(
                    SB + buf * 32768 + j * 1024 + ldsLane);
#pragma unroll
                for (int mt = 0; mt < 4; ++mt)
                    acc[g][nt][mt] = __builtin_amdgcn_mfma_f32_16x16x32_bf16(
                        afr[mt], bfr, acc[g][nt][mt], 0, 0, 0);
            }
        {   // issue group 2c+4
            const int P = 2 * c + 4;
            const char* BB = (P < 16) ? cur : b1p;
            const int PL  = P & 15;
            const int buf = (ROT + P) % 3;
#pragma unroll
            for (int j = 0; j < 4; ++j) {
                const int s = PL * 4 + j;
                const int sc = s >> 3, sg = (s >> 1) & 3, sn = s & 1;
                gload16(BB + sc * 65536 + sg * 16384 + sn * 1024 + laneByte,
                        SB + buf * 32768 + w * 4096 + j * 1024);
            }
        }
    }

    // barrier 1: all waves' A-frag LDS reads of old h done before rewrite.
    // lgkm-only drain -- the 12 staged loads stay in flight.
    asm volatile("s_waitcnt lgkmcnt(0)" ::: "memory");
    __builtin_amdgcn_s_barrier();

    // wave-local GRU update + publish h_new to Abuf
#pragma unroll
    for (int nt = 0; nt < 2; ++nt)
#pragma unroll
        for (int mt = 0; mt < 4; ++mt)
#pragma unroll
            for (int i = 0; i < 4; ++i) {
                float r  = sigmoid_f(acc[0][nt][mt][i]);
                float z  = sigmoid_f(acc[1][nt][mt][i]);
                float n  = tanh_f(acc[2][nt][mt][i] + r * acc[3][nt][mt][i]);
                float hv = n + z * (h[nt][mt][i] - n);
                h[nt][mt][i] = hv;
                Abuf[(mt * 16 + q * 4 + i) * 264 + (w * 32) + nt * 16 + l16] =
                    (bf16_t)hv;
            }

    // barrier 2: new h visible to all; lgkm-only drain.
    asm volatile("s_waitcnt lgkmcnt(0)" ::: "memory");
    __builtin_amdgcn_s_barrier();

    // y = h_new @ W_out^T + b_out ; wave w -> 16x16 tile (mt=w>>1, nt=w&1)
    floatx4 accy = {ybias, ybias, ybias, ybias};
    const int mty = w >> 1, nty = w & 1;
#pragma unroll
    for (int c = 0; c < 8; ++c) {
        bf16x8 a = *reinterpret_cast<const bf16x8*>(
            &Abuf[(mty * 16 + l16) * 264 + c * 32 + q * 8]);
        bf16x8 bw = *reinterpret_cast<const bf16x8*>(
            &WoutB[(nty * 16 + l16) * 264 + c * 32 + q * 8]);
        accy = __builtin_amdgcn_mfma_f32_16x16x32_bf16(a, bw, accy, 0, 0, 0);
    }
    const int ocol = nty * 16 + l16;
    if (ocol < OUTC) {
#pragma unroll
        for (int i = 0; i < 4; ++i) {
            int row = mty * 16 + q * 4 + i;
            out[(size_t)(rowBase + row) * (GRU_STEPS * OUTC) + t * OUTC + ocol] =
                accy[i];
        }
    }
    // no barrier here: y-phase and the next step's gate phase only READ Abuf;
    // the next write is protected by barrier 1 of step t+1.
}

// One WG (8 waves, 512 thr) per 64 batch rows; runs all 120 steps.
// Wave w owns h columns [w*32, w*32+32). B weights stream L2 -> LDS via
// global_load_lds (3 rotating 32 KB buffers, 12 KB/wave in flight, counted
// vmcnt(8), no staging barriers -- each wave stages only its own slice).
__global__ __launch_bounds__(512, 2)
void gru_main(const float* __restrict__ hidden,
              const bf16_t* __restrict__ blob0, const bf16_t* __restrict__ blob1,
              const bf16_t* __restrict__ woutp, const float* __restrict__ biasc,
              const float* __restrict__ boutp, float* __restrict__ out)
{
    __shared__ __attribute__((aligned(16))) char SB[3 * 32768]; // B staging
    __shared__ bf16_t Abuf[64 * 264];    // h tile, [row][k] bf16, padded
    __shared__ bf16_t WoutB[32 * 264];   // W_out [o][k] bf16, padded

    const int tid = threadIdx.x;
    const int w   = tid >> 6;          // wave 0..7
    const int l16 = tid & 15;          // lane & 15
    const int q   = (tid >> 4) & 3;    // lane quad
    const int rowBase = blockIdx.x * 64;
    const int colBase = w * 32;

    for (int i = tid; i < 32 * 256; i += 512) {
        int n = i >> 8, k = i & 255;
        WoutB[n * 264 + k] = woutp[i];
    }

    float biasv[4][2];
#pragma unroll
    for (int g = 0; g < 4; ++g)
#pragma unroll
        for (int nt = 0; nt < 2; ++nt)
            biasv[g][nt] = biasc[g * 256 + colBase + nt * 16 + l16];
    const float ybias = boutp[(w & 1) * 16 + l16];

    // fp32 h master in registers, mapped exactly like MFMA C-layout:
    // row = mt*16 + q*4 + i, col = colBase + nt*16 + l16
    float h[2][4][4];
#pragma unroll
    for (int nt = 0; nt < 2; ++nt)
#pragma unroll
        for (int mt = 0; mt < 4; ++mt)
#pragma unroll
            for (int i = 0; i < 4; ++i) {
                int row = mt * 16 + q * 4 + i;
                int col = colBase + nt * 16 + l16;
                float v = hidden[(rowBase + row) * 256 + col];
                h[nt][mt][i] = v;
                Abuf[row * 264 + col] = (bf16_t)v;
            }
    __syncthreads();   // also drains vmcnt to 0 before staging starts

    const char* const b0p = (const char*)blob0;
    const char* const b1p = (const char*)blob1;
    // per-lane source offset inside a slot's 1 KB region (+ wave's col slice)
    const int laneByte = (colBase + l16) * 64 + q * 16;
    // per-lane LDS read offset: wave region + lane*16
    const int ldsLane  = w * 4096 + q * 256 + l16 * 16;

    // prologue: stage groups 0,1,2 of step 0 (from blob0) into buffers 0,1,2
#pragma unroll
    for (int P = 0; P < 3; ++P)
#pragma unroll
        for (int j = 0; j < 4; ++j) {
            const int s = P * 4 + j;
            const int sc = s >> 3, sg = (s >> 1) & 3, sn = s & 1;
            gload16(b0p + sc * 65536 + sg * 16384 + sn * 1024 + laneByte,
                    SB + P * 32768 + w * 4096 + j * 1024);
        }

    for (int tt = 0; tt < GRU_STEPS; tt += 3) {
        gru_step<0>(tt,     (tt == 0) ? b0p : b1p, b1p, Abuf, WoutB, SB,
                    h, biasv, ybias, out, rowBase, w, l16, q, laneByte, ldsLane);
        gru_step<1>(tt + 1, b1p, b1p, Abuf, WoutB, SB,
                    h, biasv, ybias, out, rowBase, w, l16, q, laneByte, ldsLane);
        gru_step<2>(tt + 2, b1p, b1p, Abuf, WoutB, SB,
                    h, biasv, ybias, out, rowBase, w, l16, q, laneByte, ldsLane);
    }
}

extern "C" void kernel_launch(void* const* d_in, const int* in_sizes, int n_in,
                              void* d_out, int out_size, void* d_ws, size_t ws_size,
                              hipStream_t stream)
{
    const float* hidden = (const float*)d_in[0];
    const float* Wih    = (const float*)d_in[1];
    const float* Whh    = (const float*)d_in[2];
    const float* bih    = (const float*)d_in[3];
    const float* bhh    = (const float*)d_in[4];
    const float* Wout   = (const float*)d_in[5];
    const float* bout   = (const float*)d_in[6];
    float* out = (float*)d_out;

    char* ws = (char*)d_ws;
    bf16_t* blob0 = (bf16_t*)(ws);
    bf16_t* blob1 = (bf16_t*)(ws + 524288);
    bf16_t* woutp = (bf16_t*)(ws + 1048576);
    float*  biasc = (float*)(ws + 1064960);
    float*  boutp = (float*)(ws + 1069056);

    repack_kernel<<<1024, 256, 0, stream>>>(Wih, Whh, bih, bhh, Wout, bout,
                                            blob0, blob1, woutp, biasc, boutp);
    gru_main<<<256, 512, 0, stream>>>(hidden, blob0, blob1, woutp, biasc, boutp, out);
}

// Round 4
// 1974.923 us; speedup vs baseline: 1.5840x; 1.5840x over previous
//
#include <hip/hip_runtime.h>

typedef __bf16 bf16_t;
typedef __bf16 bf16x8 __attribute__((ext_vector_type(8)));
typedef float floatx4 __attribute__((ext_vector_type(4)));

#define GRU_STEPS 120
#define OUTC 31
#define RING 8   // B-prefetch depth (power of 2; 64 % RING == 0)

// ws layout (bytes):
//   blob0 : [0, 524288)          bf16 [8][1024][32]  step-0 weights (x=0)
//   blob1 : [524288, 1048576)    bf16 [8][1024][32]  steady-state weights
//   woutp : [1048576, 1064960)   bf16 [32][256]      W_out padded to 32 rows
//   biasc : [1064960, 1069056)   f32  [1024]         combined gate biases
//   boutp : [1069056, 1069184)   f32  [32]           b_out padded

__global__ void repack_kernel(const float* __restrict__ Wih, const float* __restrict__ Whh,
                              const float* __restrict__ bih, const float* __restrict__ bhh,
                              const float* __restrict__ Wout, const float* __restrict__ bout,
                              bf16_t* __restrict__ blob0, bf16_t* __restrict__ blob1,
                              bf16_t* __restrict__ woutp, float* __restrict__ biasc,
                              float* __restrict__ boutp)
{
    int idx = blockIdx.x * blockDim.x + threadIdx.x;   // 0 .. 1024*256-1
    if (idx >= 1024 * 256) return;
    int n  = idx >> 8;    // blob column (gate output index), 0..1023
    int kk = idx & 255;   // k index, 0..255

    // blob column map: [0,512) r|z combined, [512,768) i_n (W_ih rows 512..767),
    //                  [768,1024) h_n (W_hh rows 512..767)
    float vih = (n < 768) ? Wih[n * 256 + kk] : 0.f;
    float vhh = (n < 512) ? Whh[n * 256 + kk]
                          : ((n >= 768) ? Whh[(n - 256) * 256 + kk] : 0.f);
    float b1 = (n < 512) ? (vih + vhh) : ((n < 768) ? vih : vhh); // t>=1 (x==h)
    float b0 = (n < 512) ? vhh : ((n < 768) ? 0.f : vhh);         // t==0 (x==0)

    int c = kk >> 5, kloc = kk & 31;
    int off = c * (1024 * 32) + n * 32 + kloc;   // [chunk][n][k] k-contiguous
    blob0[off] = (bf16_t)b0;
    blob1[off] = (bf16_t)b1;

    if (n < 32) woutp[n * 256 + kk] = (bf16_t)((n < OUTC) ? Wout[n * 256 + kk] : 0.f);
    if (idx < 1024) {
        float bb = (idx < 512) ? (bih[idx] + bhh[idx])
                               : ((idx < 768) ? bih[idx] : bhh[idx - 256]);
        biasc[idx] = bb;
    }
    if (idx < 32) boutp[idx] = (idx < OUTC) ? bout[idx] : 0.f;
}

__device__ __forceinline__ float sigmoid_f(float x) {
    return __builtin_amdgcn_rcpf(1.f + __expf(-x));
}
__device__ __forceinline__ float tanh_f(float x) {
    // 1 - 2/(1+e^{2x}): exact at +/-inf, monotone, ~1ulp rcp/exp
    return 1.f - 2.f * __builtin_amdgcn_rcpf(1.f + __expf(2.f * x));
}

// One WG (8 waves, 512 thr) per 64 batch rows; runs all 120 steps.
// Wave w owns h columns [w*32, w*32+32).
//
// Register budget (the R1 spill fix): acc[4][2][4] = 128 AGPRs is irreducible
// (all 4 gates x 64 rows accumulate against one pass of the B stream), so the
// ARCH side must fit in 128. The fp32 h master (32 VGPRs in R1 -> overflow ->
// ~1.9 GB/dispatch scratch traffic) moves to thread-private LDS slots
// (hT[tid][33], f32, b128 quads, uniform 2-way banking = free). Numerics are
// bit-identical: h round-trips LDS in full fp32.
//
// B weights stream from L2 through a RING-deep register ring (1 KB coalesced
// load per slot) kept in flight ACROSS the per-step barriers: in-loop
// barriers are raw s_barrier with an lgkmcnt(0)-only drain.
__global__ __launch_bounds__(512, 2)
void gru_main(const float* __restrict__ hidden,
              const bf16_t* __restrict__ blob0, const bf16_t* __restrict__ blob1,
              const bf16_t* __restrict__ woutp, const float* __restrict__ biasc,
              const float* __restrict__ boutp, float* __restrict__ out)
{
    __shared__ bf16_t Abuf[64 * 264];    // h tile, [row][k] bf16, padded
    __shared__ bf16_t WoutB[32 * 264];   // W_out [o][k] bf16, padded
    __shared__ float  hT[512 * 33];      // fp32 h master, thread-private slots

    const int tid = threadIdx.x;
    const int w   = tid >> 6;          // wave 0..7
    const int l16 = tid & 15;          // lane & 15
    const int q   = (tid >> 4) & 3;    // lane quad
    const int rowBase = blockIdx.x * 64;
    const int colBase = w * 32;

    for (int i = tid; i < 32 * 256; i += 512) {
        int n = i >> 8, k = i & 255;
        WoutB[n * 264 + k] = woutp[i];
    }

    float biasv[4][2];
#pragma unroll
    for (int g = 0; g < 4; ++g)
#pragma unroll
        for (int nt = 0; nt < 2; ++nt)
            biasv[g][nt] = biasc[g * 256 + colBase + nt * 16 + l16];
    const float ybias = boutp[(w & 1) * 16 + l16];

    // init: h0 -> hT (fp32 quads) + Abuf (bf16). Element (nt,mt,i) lives at
    // row = mt*16 + q*4 + i, col = colBase + nt*16 + l16 (MFMA C-layout).
#pragma unroll
    for (int nt = 0; nt < 2; ++nt)
#pragma unroll
        for (int mt = 0; mt < 4; ++mt) {
            floatx4 hq;
#pragma unroll
            for (int i = 0; i < 4; ++i) {
                int row = mt * 16 + q * 4 + i;
                int col = colBase + nt * 16 + l16;
                hq[i] = hidden[(rowBase + row) * 256 + col];
                Abuf[row * 264 + col] = (bf16_t)hq[i];
            }
            *reinterpret_cast<floatx4*>(&hT[tid * 33 + (nt * 4 + mt) * 4]) = hq;
        }
    __syncthreads();

    // B slot s (0..63) = c*8 + g*2 + nt. Per-lane byte offset in a step blob:
    //   c*65536 + g*16384 + nt*1024 + (colBase + l16)*64 + q*16
    // Each wave slot read is one contiguous 1 KB region -> fully coalesced.
    const char* const b0p = (const char*)blob0;
    const char* const b1p = (const char*)blob1;
    const int laneByte = (colBase + l16) * 64 + q * 16;

    bf16x8 ring[RING];

    // prologue: slots 0..RING-1 of step 0 (from blob0)
#pragma unroll
    for (int s = 0; s < RING; ++s) {
        const int c = s >> 3, g = (s >> 1) & 3, nt = s & 1;
        ring[s] = *reinterpret_cast<const bf16x8*>(
            b0p + c * 65536 + g * 16384 + nt * 1024 + laneByte);
    }

    for (int t = 0; t < GRU_STEPS; ++t) {
        const char* const cur = (t == 0) ? b0p : b1p;

        // acc[g][nt][mt]: gate-group g, 16-col subtile nt, 16-row tile mt.
        floatx4 acc[4][2][4];
#pragma unroll
        for (int g = 0; g < 4; ++g)
#pragma unroll
            for (int nt = 0; nt < 2; ++nt) {
                float b = biasv[g][nt];
                floatx4 binit = {b, b, b, b};
#pragma unroll
                for (int mt = 0; mt < 4; ++mt) acc[g][nt][mt] = binit;
            }

#pragma unroll
        for (int c = 0; c < 8; ++c) {      // K chunks of 32
            bf16x8 afr[4];
#pragma unroll
            for (int mt = 0; mt < 4; ++mt)
                afr[mt] = *reinterpret_cast<const bf16x8*>(
                    &Abuf[(mt * 16 + l16) * 264 + c * 32 + q * 8]);
#pragma unroll
            for (int g = 0; g < 4; ++g)
#pragma unroll
                for (int nt = 0; nt < 2; ++nt) {
                    const int s = c * 8 + g * 2 + nt;
                    const bf16x8 bfr = ring[s & (RING - 1)];
#pragma unroll
                    for (int mt = 0; mt < 4; ++mt)
                        acc[g][nt][mt] = __builtin_amdgcn_mfma_f32_16x16x32_bf16(
                            afr[mt], bfr, acc[g][nt][mt], 0, 0, 0);
                    // refill ring with slot s+RING (spills into next step,
                    // which always reads blob1; compile-time branch)
                    const int u = s + RING;
                    if (u < 64) {
                        const int uc = u >> 3, ug = (u >> 1) & 3, un = u & 1;
                        ring[s & (RING - 1)] = *reinterpret_cast<const bf16x8*>(
                            cur + uc * 65536 + ug * 16384 + un * 1024 + laneByte);
                    } else {
                        const int uu = u - 64;
                        const int uc = uu >> 3, ug = (uu >> 1) & 3, un = uu & 1;
                        ring[s & (RING - 1)] = *reinterpret_cast<const bf16x8*>(
                            b1p + uc * 65536 + ug * 16384 + un * 1024 + laneByte);
                    }
                }
        }
        // barrier 1: all waves' A-frag LDS reads of old h done before rewrite.
        // lgkm-only drain -- ring global loads stay in flight.
        asm volatile("s_waitcnt lgkmcnt(0)" ::: "memory");
        __builtin_amdgcn_s_barrier();

        // wave-local GRU update: stream h quads LDS->reg->LDS, publish bf16
#pragma unroll
        for (int nt = 0; nt < 2; ++nt)
#pragma unroll
            for (int mt = 0; mt < 4; ++mt) {
                floatx4 hq = *reinterpret_cast<const floatx4*>(
                    &hT[tid * 33 + (nt * 4 + mt) * 4]);
#pragma unroll
                for (int i = 0; i < 4; ++i) {
                    float r  = sigmoid_f(acc[0][nt][mt][i]);
                    float z  = sigmoid_f(acc[1][nt][mt][i]);
                    float n  = tanh_f(acc[2][nt][mt][i] + r * acc[3][nt][mt][i]);
                    float hv = n + z * (hq[i] - n);
                    hq[i] = hv;
                    Abuf[(mt * 16 + q * 4 + i) * 264 + colBase + nt * 16 + l16] =
                        (bf16_t)hv;
                }
                *reinterpret_cast<floatx4*>(
                    &hT[tid * 33 + (nt * 4 + mt) * 4]) = hq;
            }

        // barrier 2: new h visible to all; again lgkm-only drain.
        asm volatile("s_waitcnt lgkmcnt(0)" ::: "memory");
        __builtin_amdgcn_s_barrier();

        // y = h_new @ W_out^T + b_out ; wave w -> 16x16 tile (mt=w>>1, nt=w&1)
        floatx4 accy = {ybias, ybias, ybias, ybias};
        const int mty = w >> 1, nty = w & 1;
#pragma unroll
        for (int c = 0; c < 8; ++c) {
            bf16x8 a = *reinterpret_cast<const bf16x8*>(
                &Abuf[(mty * 16 + l16) * 264 + c * 32 + q * 8]);
            bf16x8 bw = *reinterpret_cast<const bf16x8*>(
                &WoutB[(nty * 16 + l16) * 264 + c * 32 + q * 8]);
            accy = __builtin_amdgcn_mfma_f32_16x16x32_bf16(a, bw, accy, 0, 0, 0);
        }
        const int ocol = nty * 16 + l16;
        if (ocol < OUTC) {
#pragma unroll
            for (int i = 0; i < 4; ++i) {
                int row = mty * 16 + q * 4 + i;
                out[(size_t)(rowBase + row) * (GRU_STEPS * OUTC) + t * OUTC + ocol] =
                    accy[i];
            }
        }
        // no barrier here: y-phase and the next step's gate phase only READ
        // Abuf; the next write is protected by barrier 1 of step t+1.
    }
}

extern "C" void kernel_launch(void* const* d_in, const int* in_sizes, int n_in,
                              void* d_out, int out_size, void* d_ws, size_t ws_size,
                              hipStream_t stream)
{
    const float* hidden = (const float*)d_in[0];
    const float* Wih    = (const float*)d_in[1];
    const float* Whh    = (const float*)d_in[2];
    const float* bih    = (const float*)d_in[3];
    const float* bhh    = (const float*)d_in[4];
    const float* Wout   = (const float*)d_in[5];
    const float* bout   = (const float*)d_in[6];
    float* out = (float*)d_out;

    char* ws = (char*)d_ws;
    bf16_t* blob0 = (bf16_t*)(ws);
    bf16_t* blob1 = (bf16_t*)(ws + 524288);
    bf16_t* woutp = (bf16_t*)(ws + 1048576);
    float*  biasc = (float*)(ws + 1064960);
    float*  boutp = (float*)(ws + 1069056);

    repack_kernel<<<1024, 256, 0, stream>>>(Wih, Whh, bih, bhh, Wout, bout,
                                            blob0, blob1, woutp, biasc, boutp);
    gru_main<<<256, 512, 0, stream>>>(hidden, blob0, blob1, woutp, biasc, boutp, out);
}

// Round 7
// 1634.759 us; speedup vs baseline: 1.9136x; 1.2081x over previous
//
#include <hip/hip_runtime.h>

typedef __bf16 bf16_t;
typedef __bf16 bf16x8 __attribute__((ext_vector_type(8)));
typedef float floatx4 __attribute__((ext_vector_type(4)));

#define GRU_STEPS 120
#define OUTC 31
#define RING 16   // B-prefetch depth (power of 2; 64 % RING == 0)

// ws layout (bytes):
//   blob0 : [0, 524288)          bf16 [8][1024][32]  step-0 weights (x=0)
//   blob1 : [524288, 1048576)    bf16 [8][1024][32]  steady-state weights
//   woutp : [1048576, 1064960)   bf16 [32][256]      W_out padded to 32 rows
//   biasc : [1064960, 1069056)   f32  [1024]         combined gate biases
//   boutp : [1069056, 1069184)   f32  [32]           b_out padded

__global__ void repack_kernel(const float* __restrict__ Wih, const float* __restrict__ Whh,
                              const float* __restrict__ bih, const float* __restrict__ bhh,
                              const float* __restrict__ Wout, const float* __restrict__ bout,
                              bf16_t* __restrict__ blob0, bf16_t* __restrict__ blob1,
                              bf16_t* __restrict__ woutp, float* __restrict__ biasc,
                              float* __restrict__ boutp)
{
    int idx = blockIdx.x * blockDim.x + threadIdx.x;   // 0 .. 1024*256-1
    if (idx >= 1024 * 256) return;
    int n  = idx >> 8;    // blob column (gate output index), 0..1023
    int kk = idx & 255;   // k index, 0..255

    // blob column map: [0,512) r|z combined, [512,768) i_n (W_ih rows 512..767),
    //                  [768,1024) h_n (W_hh rows 512..767)
    float vih = (n < 768) ? Wih[n * 256 + kk] : 0.f;
    float vhh = (n < 512) ? Whh[n * 256 + kk]
                          : ((n >= 768) ? Whh[(n - 256) * 256 + kk] : 0.f);
    float b1 = (n < 512) ? (vih + vhh) : ((n < 768) ? vih : vhh); // t>=1 (x==h)
    float b0 = (n < 512) ? vhh : ((n < 768) ? 0.f : vhh);         // t==0 (x==0)

    int c = kk >> 5, kloc = kk & 31;
    int off = c * (1024 * 32) + n * 32 + kloc;   // [chunk][n][k] k-contiguous
    blob0[off] = (bf16_t)b0;
    blob1[off] = (bf16_t)b1;

    if (n < 32) woutp[n * 256 + kk] = (bf16_t)((n < OUTC) ? Wout[n * 256 + kk] : 0.f);
    if (idx < 1024) {
        float bb = (idx < 512) ? (bih[idx] + bhh[idx])
                               : ((idx < 768) ? bih[idx] : bhh[idx - 256]);
        biasc[idx] = bb;
    }
    if (idx < 32) boutp[idx] = (idx < OUTC) ? bout[idx] : 0.f;
}

__device__ __forceinline__ float sigmoid_f(float x) {
    return __builtin_amdgcn_rcpf(1.f + __expf(-x));
}
__device__ __forceinline__ float tanh_f(float x) {
    // 1 - 2/(1+e^{2x}): exact at +/-inf, monotone, ~1ulp rcp/exp
    return 1.f - 2.f * __builtin_amdgcn_rcpf(1.f + __expf(2.f * x));
}

// One WG (8 waves, 512 thr) per 64 batch rows; runs all 120 steps.
// Wave w owns h columns [w*32, w*32+32).
//
// Register shape (evidence R1/R2/R4: arch overflow => ~2 GB scratch traffic):
//  - gate phase split over nt (two 16-col subtiles): acc[4][4] = 64 AGPRs
//    live at a time instead of 128. Each slice's GRU update (register+hT)
//    runs right after its gates, freeing the accumulators.
//  - fp32 h master lives in thread-private LDS slots (hT[tid][33], b128
//    quads) -- bit-exact round trip, zero arch VGPR cost.
//  - freed budget goes to RING=16: B-slot consume order k = nt*32+c*4+g is
//    strictly sequential, so the ring is a 16-deep FIFO; issue->use distance
//    = 16 slots ~ 64 MFMAs, covering loaded L2 latency (the R4 limiter;
//    dur x MfmaUtil == const ~467us across R0-R4 says all remaining time is
//    stall, and RING=8's 8-slot distance was below L2 latency).
//
// The t-loop is pinned to unroll 1 (the body is ~2k instructions; letting
// the compiler unroll 120 iterations would explode compile time/code size).
// The t==0 blob select is peeled into a rotating pointer so the body is
// t-invariant and branch-free.
//
// In-loop barriers are raw s_barrier with lgkmcnt(0)-only drain: the ring's
// global loads stay in flight across them (vmcnt never force-drained).
__global__ __launch_bounds__(512, 2)
void gru_main(const float* __restrict__ hidden,
              const bf16_t* __restrict__ blob0, const bf16_t* __restrict__ blob1,
              const bf16_t* __restrict__ woutp, const float* __restrict__ biasc,
              const float* __restrict__ boutp, float* __restrict__ out)
{
    __shared__ bf16_t Abuf[64 * 264];    // h tile, [row][k] bf16, padded
    __shared__ bf16_t WoutB[32 * 264];   // W_out [o][k] bf16, padded
    __shared__ float  hT[512 * 33];      // fp32 h master, thread-private slots

    const int tid = threadIdx.x;
    const int w   = tid >> 6;          // wave 0..7
    const int l16 = tid & 15;          // lane & 15
    const int q   = (tid >> 4) & 3;    // lane quad
    const int rowBase = blockIdx.x * 64;
    const int colBase = w * 32;

    for (int i = tid; i < 32 * 256; i += 512) {
        int n = i >> 8, k = i & 255;
        WoutB[n * 264 + k] = woutp[i];
    }

    float biasv[4][2];
#pragma unroll
    for (int g = 0; g < 4; ++g)
#pragma unroll
        for (int nt = 0; nt < 2; ++nt)
            biasv[g][nt] = biasc[g * 256 + colBase + nt * 16 + l16];
    const float ybias = boutp[(w & 1) * 16 + l16];

    // init: h0 -> hT (fp32 quads) + Abuf (bf16). Element (nt,mt,i) lives at
    // row = mt*16 + q*4 + i, col = colBase + nt*16 + l16 (MFMA C-layout).
#pragma unroll
    for (int nt = 0; nt < 2; ++nt)
#pragma unroll
        for (int mt = 0; mt < 4; ++mt) {
            floatx4 hq;
#pragma unroll
            for (int i = 0; i < 4; ++i) {
                int row = mt * 16 + q * 4 + i;
                int col = colBase + nt * 16 + l16;
                hq[i] = hidden[(rowBase + row) * 256 + col];
                Abuf[row * 264 + col] = (bf16_t)hq[i];
            }
            *reinterpret_cast<floatx4*>(&hT[tid * 33 + (nt * 4 + mt) * 4]) = hq;
        }
    __syncthreads();

    // B slot k (0..63) = nt*32 + c*4 + g (consume order == this order).
    // Per-lane byte offset in a step blob:
    //   c*65536 + g*16384 + nt*1024 + (colBase + l16)*64 + q*16
    // Each wave slot read is one contiguous 1 KB region -> fully coalesced.
    const char* const b0p = (const char*)blob0;
    const char* const b1p = (const char*)blob1;
    const int laneByte = (colBase + l16) * 64 + q * 16;

    bf16x8 ring[RING];

    // prologue: slots 0..RING-1 of step 0 (from blob0)
#pragma unroll
    for (int s = 0; s < RING; ++s) {
        const int nt = s >> 5, c = (s >> 2) & 7, g = s & 3;
        ring[s] = *reinterpret_cast<const bf16x8*>(
            b0p + c * 65536 + g * 16384 + nt * 1024 + laneByte);
    }

    // cur = blob for step t (only t=0 differs); nxt = blob for step t+1.
    const char* cur = b0p;

#pragma unroll 1
    for (int t = 0; t < GRU_STEPS; ++t) {

        // ---- gate phase + hT-local update, one nt-slice at a time ----
#pragma unroll
        for (int nt = 0; nt < 2; ++nt) {
            floatx4 acc[4][4];     // [g][mt] -- 64 AGPRs live
#pragma unroll
            for (int g = 0; g < 4; ++g) {
                float b = biasv[g][nt];
                floatx4 binit = {b, b, b, b};
#pragma unroll
                for (int mt = 0; mt < 4; ++mt) acc[g][mt] = binit;
            }

#pragma unroll
            for (int c = 0; c < 8; ++c) {      // K chunks of 32
                bf16x8 afr[4];
#pragma unroll
                for (int mt = 0; mt < 4; ++mt)
                    afr[mt] = *reinterpret_cast<const bf16x8*>(
                        &Abuf[(mt * 16 + l16) * 264 + c * 32 + q * 8]);
#pragma unroll
                for (int g = 0; g < 4; ++g) {
                    const int k = nt * 32 + c * 4 + g;
                    const bf16x8 bfr = ring[k & (RING - 1)];
#pragma unroll
                    for (int mt = 0; mt < 4; ++mt)
                        acc[g][mt] = __builtin_amdgcn_mfma_f32_16x16x32_bf16(
                            afr[mt], bfr, acc[g][mt], 0, 0, 0);
                    // refill ring with slot k+RING (slots >=64 belong to the
                    // next step, which always reads blob1; compile-time branch)
                    const int u = k + RING;
                    if (u < 64) {
                        const int uc = (u >> 2) & 7, ug = u & 3, un = u >> 5;
                        ring[k & (RING - 1)] = *reinterpret_cast<const bf16x8*>(
                            cur + uc * 65536 + ug * 16384 + un * 1024 + laneByte);
                    } else {
                        const int uu = u - 64;
                        const int uc = (uu >> 2) & 7, ug = uu & 3, un = uu >> 5;
                        ring[k & (RING - 1)] = *reinterpret_cast<const bf16x8*>(
                            b1p + uc * 65536 + ug * 16384 + un * 1024 + laneByte);
                    }
                }
            }

            // GRU update for this nt-slice: hT round-trip in fp32 (thread-
            // private -> no sync needed). Abuf publish deferred to after
            // barrier 1 (other waves still read old Abuf in their gate phase).
#pragma unroll
            for (int mt = 0; mt < 4; ++mt) {
                floatx4 hq = *reinterpret_cast<const floatx4*>(
                    &hT[tid * 33 + (nt * 4 + mt) * 4]);
#pragma unroll
                for (int i = 0; i < 4; ++i) {
                    float r  = sigmoid_f(acc[0][mt][i]);
                    float z  = sigmoid_f(acc[1][mt][i]);
                    float n  = tanh_f(acc[2][mt][i] + r * acc[3][mt][i]);
                    hq[i] = n + z * (hq[i] - n);
                }
                *reinterpret_cast<floatx4*>(
                    &hT[tid * 33 + (nt * 4 + mt) * 4]) = hq;
            }
        }

        // barrier 1: all waves' A-frag reads of old h done before rewrite.
        // lgkm-only drain -- ring global loads stay in flight.
        asm volatile("s_waitcnt lgkmcnt(0)" ::: "memory");
        __builtin_amdgcn_s_barrier();

        // publish h_new (from hT) to Abuf as bf16
#pragma unroll
        for (int nt = 0; nt < 2; ++nt)
#pragma unroll
            for (int mt = 0; mt < 4; ++mt) {
                floatx4 hq = *reinterpret_cast<const floatx4*>(
                    &hT[tid * 33 + (nt * 4 + mt) * 4]);
#pragma unroll
                for (int i = 0; i < 4; ++i)
                    Abuf[(mt * 16 + q * 4 + i) * 264 + colBase + nt * 16 + l16] =
                        (bf16_t)hq[i];
            }

        // barrier 2: new h visible to all; again lgkm-only drain.
        asm volatile("s_waitcnt lgkmcnt(0)" ::: "memory");
        __builtin_amdgcn_s_barrier();

        // y = h_new @ W_out^T + b_out ; wave w -> 16x16 tile (mt=w>>1, nt=w&1)
        floatx4 accy = {ybias, ybias, ybias, ybias};
        const int mty = w >> 1, nty = w & 1;
#pragma unroll
        for (int c = 0; c < 8; ++c) {
            bf16x8 a = *reinterpret_cast<const bf16x8*>(
                &Abuf[(mty * 16 + l16) * 264 + c * 32 + q * 8]);
            bf16x8 bw = *reinterpret_cast<const bf16x8*>(
                &WoutB[(nty * 16 + l16) * 264 + c * 32 + q * 8]);
            accy = __builtin_amdgcn_mfma_f32_16x16x32_bf16(a, bw, accy, 0, 0, 0);
        }
        const int ocol = nty * 16 + l16;
        if (ocol < OUTC) {
#pragma unroll
            for (int i = 0; i < 4; ++i) {
                int row = mty * 16 + q * 4 + i;
                out[(size_t)(rowBase + row) * (GRU_STEPS * OUTC) + t * OUTC + ocol] =
                    accy[i];
            }
        }
        // no barrier here: y-phase and the next step's gate phase only READ
        // Abuf; the next write is protected by barrier 1 of step t+1.

        cur = b1p;   // steps >=1 read the steady-state blob
    }
}

extern "C" void kernel_launch(void* const* d_in, const int* in_sizes, int n_in,
                              void* d_out, int out_size, void* d_ws, size_t ws_size,
                              hipStream_t stream)
{
    const float* hidden = (const float*)d_in[0];
    const float* Wih    = (const float*)d_in[1];
    const float* Whh    = (const float*)d_in[2];
    const float* bih    = (const float*)d_in[3];
    const float* bhh    = (const float*)d_in[4];
    const float* Wout   = (const float*)d_in[5];
    const float* bout   = (const float*)d_in[6];
    float* out = (float*)d_out;

    char* ws = (char*)d_ws;
    bf16_t* blob0 = (bf16_t*)(ws);
    bf16_t* blob1 = (bf16_t*)(ws + 524288);
    bf16_t* woutp = (bf16_t*)(ws + 1048576);
    float*  biasc = (float*)(ws + 1064960);
    float*  boutp = (float*)(ws + 1069056);

    repack_kernel<<<1024, 256, 0, stream>>>(Wih, Whh, bih, bhh, Wout, bout,
                                            blob0, blob1, woutp, biasc, boutp);
    gru_main<<<256, 512, 0, stream>>>(hidden, blob0, blob1, woutp, biasc, boutp, out);
}